// Round 4
// baseline (532.999 us; speedup 1.0000x reference)
//
#include <hip/hip_runtime.h>
#include <hip/hip_cooperative_groups.h>
#include <stdint.h>

namespace cg = cooperative_groups;

#define B_N 16384
#define H_N 256
#define IN_W 258
#define GX_N 70
#define GY_N 70
#define SW_N 2
#define KK_N 25

typedef __bf16 bf16x8 __attribute__((ext_vector_type(8)));
typedef __bf16 bf16x4 __attribute__((ext_vector_type(4)));
typedef __bf16 bf16x2 __attribute__((ext_vector_type(2)));
typedef float f32x4 __attribute__((ext_vector_type(4)));

#define AS1 __attribute__((address_space(1)))
#define AS3 __attribute__((address_space(3)))

static __device__ __forceinline__ void gload16(const void* g, void* l) {
    __builtin_amdgcn_global_load_lds((const AS1 uint32_t*)g, (AS3 uint32_t*)l, 16, 0, 0);
}

// ---- ws layout (bf16 elements) ----
// AB    at 0        : [16384][512]  ([feat|hid])
// wfull at 8388608  : [1024][512]   rows j=c*256+col, c in {r,i,s,n};
//                     k<256 -> wih[base_c+col][k], k>=256 -> whh[base_c+col][k-256]
//                     base_c = {0,256,768,512}
// woutB at 8912896  : [256][512]
// comb  at 9043968  : [16384][512]  ([mix|q])
// ugsg  at 17432576 : [16384][256][2] (ug,sg interleaved)
#define E_AB   8388608ULL
#define E_WF   8912896ULL
#define E_WOUT 9043968ULL
#define E_COMB 9043968ULL
#define E_UGSG 17432576ULL

__global__ __launch_bounds__(256) void fused_kernel(
    const float* __restrict__ in_t, const float* __restrict__ hid,
    const float* __restrict__ wih, const float* __restrict__ b_ih,
    const float* __restrict__ whh, const float* __restrict__ b_hh,
    const float* __restrict__ wout, const float* __restrict__ b_out,
    const float* __restrict__ memory, float* __restrict__ out,
    __bf16* __restrict__ base)
{
    __shared__ __bf16 smem[8192];  // 16 KB, shared by gates/out phases
    cg::grid_group grid = cg::this_grid();
    const int nb = gridDim.x;
    const int bid = blockIdx.x;
    const int t = threadIdx.x;
    const int lane = t & 63, w = t >> 6;
    const int lr = lane & 15, seg = lane >> 4;

    __bf16* AB    = base;
    __bf16* wfull = base + E_AB;
    __bf16* woutB = base + E_WF;
    __bf16* comb  = base + E_COMB;
    __bf16* ugsg  = base + E_UGSG;

    // ================= phase 0: cast fp32 -> bf16 staging =================
    {
        size_t g = (size_t)bid * 256 + t;
        size_t stride = (size_t)nb * 256;
        for (size_t e = g * 4; e < E_WOUT; e += stride * 4) {
            const float* src;
            if (e < E_AB) {
                size_t row = e >> 9;
                size_t c = e & 511;
                src = (c < 256) ? (in_t + row * IN_W + c) : (hid + row * 256 + (c - 256));
            } else if (e < E_WF) {
                size_t off = e - E_AB;
                size_t j = off >> 9;
                size_t k = off & 511;
                size_t c = j >> 8;
                size_t col = j & 255;
                size_t cb = (c == 0) ? 0 : (c == 1) ? 256 : (c == 2) ? 768 : 512;
                const float* srcm = (k < 256) ? wih : whh;
                src = srcm + (cb + col) * 256 + (k & 255);
            } else {
                src = wout + (e - E_WF);
            }
            bf16x4 o;
            o.x = (__bf16)src[0];
            o.y = (__bf16)src[1];
            o.z = (__bf16)src[2];
            o.w = (__bf16)src[3];
            *reinterpret_cast<bf16x4*>(base + e) = o;
        }
    }
    grid.sync();

    // ================= phase 1: gates GEMM (K=512 concat) =================
    // 1024 tiles: rx in 0..127 (128 rows each), hy in 0..7 (32 cols each).
    // tile%8 stays == bid%8 across grid-stride passes (nb % 8 == 0) -> XCD affinity.
    for (int tile = bid; tile < 1024; tile += nb) {
        int j = tile >> 3;
        int rb = ((tile & 7) | ((j & 15) << 3)) << 7;  // rx*128
        int h0 = (j >> 4) << 5;                         // hy*32

        __bf16* ldsA = smem;
        __bf16* ldsB = smem + 4096;
        const int r_s = t & 127;
        const int s_lo = t >> 7;
        const __bf16* gA = AB + (size_t)(rb + r_s) * 512 + s_lo * 8;
        const int wr = ((r_s >> 5) << 8) + h0 + (r_s & 31);
        const __bf16* gB = wfull + (size_t)wr * 512 + s_lo * 8;
        __bf16* lA = ldsA + t * 8;
        __bf16* lB = ldsB + t * 8;

        f32x4 acc_s[3][2][2], acc_ni[2][2], acc_nh[2][2];
#pragma unroll
        for (int hh = 0; hh < 2; hh++)
#pragma unroll
            for (int rh = 0; rh < 2; rh++) {
#pragma unroll
                for (int c = 0; c < 3; c++) acc_s[c][hh][rh] = (f32x4){0.f, 0.f, 0.f, 0.f};
                acc_ni[hh][rh] = (f32x4){0.f, 0.f, 0.f, 0.f};
                acc_nh[hh][rh] = (f32x4){0.f, 0.f, 0.f, 0.f};
            }

#pragma unroll 1
        for (int half = 0; half < 2; half++) {
            for (int kt = half * 256; kt < half * 256 + 256; kt += 32) {
                gload16(gA + kt, lA);
                gload16(gA + kt + 16, lA + 2048);
                gload16(gB + kt, lB);
                gload16(gB + kt + 16, lB + 2048);
                __syncthreads();

                bf16x8 af[2];
#pragma unroll
                for (int rh = 0; rh < 2; rh++) {
                    int tr = w * 32 + rh * 16 + lr;
                    af[rh] = *reinterpret_cast<const bf16x8*>(ldsA + seg * 1024 + tr * 8);
                }
#pragma unroll
                for (int c = 0; c < 4; c++)
#pragma unroll
                    for (int hh = 0; hh < 2; hh++) {
                        int br = c * 32 + hh * 16 + lr;
                        bf16x8 bb = *reinterpret_cast<const bf16x8*>(ldsB + seg * 1024 + br * 8);
#pragma unroll
                        for (int rh = 0; rh < 2; rh++) {
                            if (c < 3)
                                acc_s[c][hh][rh] = __builtin_amdgcn_mfma_f32_16x16x32_bf16(af[rh], bb, acc_s[c][hh][rh], 0, 0, 0);
                            else if (half == 0)
                                acc_ni[hh][rh] = __builtin_amdgcn_mfma_f32_16x16x32_bf16(af[rh], bb, acc_ni[hh][rh], 0, 0, 0);
                            else
                                acc_nh[hh][rh] = __builtin_amdgcn_mfma_f32_16x16x32_bf16(af[rh], bb, acc_nh[hh][rh], 0, 0, 0);
                        }
                    }
                __syncthreads();
            }
        }

#pragma unroll
        for (int hh = 0; hh < 2; hh++) {
            int col = h0 + hh * 16 + lr;
            float br_ = b_ih[col] + b_hh[col];
            float bi_ = b_ih[col + 256] + b_hh[col + 256];
            float bs_ = b_ih[col + 768] + b_hh[col + 768];
            float bni = b_ih[col + 512];
            float bnh = b_hh[col + 512];
#pragma unroll
            for (int rh = 0; rh < 2; rh++) {
#pragma unroll
                for (int r = 0; r < 4; r++) {
                    int row = rb + w * 32 + rh * 16 + seg * 4 + r;
                    float sr = acc_s[0][hh][rh][r] + br_;
                    float si = acc_s[1][hh][rh][r] + bi_;
                    float ss = acc_s[2][hh][rh][r] + bs_;
                    float ni = acc_ni[hh][rh][r] + bni;
                    float nh = acc_nh[hh][rh][r] + bnh;
                    float rg = 1.f / (1.f + __expf(-sr));
                    float ug = 1.f / (1.f + __expf(-si));
                    float sg = 1.f / (1.f + __expf(-ss));
                    float ng = tanhf(ni + rg * nh);
                    comb[(size_t)row * 512 + 256 + col] = (__bf16)ng;
                    bf16x2 us;
                    us.x = (__bf16)ug;
                    us.y = (__bf16)sg;
                    *reinterpret_cast<bf16x2*>(ugsg + ((size_t)row * 256 + col) * 2) = us;
                }
            }
        }
    }
    grid.sync();

    // ================= phase 2: attention (online softmax) =================
    for (int b0 = bid; b0 < 4096; b0 += nb) {
        int b = b0 * 4 + w;
        const float* row_in = in_t + (size_t)b * IN_W;
        int gx = (int)row_in[256] + SW_N;
        int gy = (int)row_in[257] + SW_N;
        gx = min(max(gx, 0), GX_N - 1);
        gy = min(max(gy, 0), GY_N - 1);

        bf16x4 qb = *reinterpret_cast<const bf16x4*>(comb + (size_t)b * 512 + 256 + lane * 4);
        float q0 = (float)qb.x, q1 = (float)qb.y, q2 = (float)qb.z, q3 = (float)qb.w;

        float m = -INFINITY, d = 0.f;
        float o0 = 0.f, o1 = 0.f, o2 = 0.f, o3 = 0.f;
#pragma unroll
        for (int k = 0; k < KK_N; k++) {
            int i = k / 5, jj = k % 5;
            int xi = min(max(gx + i - SW_N, 0), GX_N - 1);
            int yj = min(max(gy + jj - SW_N, 0), GY_N - 1);
            const f32x4* cp = reinterpret_cast<const f32x4*>(memory + ((size_t)xi * GY_N + yj) * H_N);
            f32x4 v = cp[lane];
            float p = q0 * v.x + q1 * v.y + q2 * v.z + q3 * v.w;
            for (int off = 32; off; off >>= 1) p += __shfl_xor(p, off, 64);
            float a = (p == 0.f) ? -INFINITY : p;
            float mn = fmaxf(m, a);
            if (mn != -INFINITY) {
                float alpha = __expf(m - mn);
                float e = __expf(a - mn);
                d = d * alpha + e;
                o0 = o0 * alpha + e * v.x;
                o1 = o1 * alpha + e * v.y;
                o2 = o2 * alpha + e * v.z;
                o3 = o3 * alpha + e * v.w;
                m = mn;
            }
        }
        float inv = (d != 0.f) ? 1.f / d : 0.f;
        bf16x4 ob;
        ob.x = (__bf16)(o0 * inv);
        ob.y = (__bf16)(o1 * inv);
        ob.z = (__bf16)(o2 * inv);
        ob.w = (__bf16)(o3 * inv);
        *reinterpret_cast<bf16x4*>(comb + (size_t)b * 512 + lane * 4) = ob;
    }
    grid.sync();

    // ================= phase 3: out GEMM (K=512) + blend =================
    // 1024 tiles: rx in 0..255 (64 rows), cy in 0..3 (64 cols).
    for (int tile = bid; tile < 1024; tile += nb) {
        int j = tile >> 3;
        int rx = (tile & 7) | ((j & 31) << 3);
        int cy = j >> 5;
        int rb = rx << 6;
        int n0 = cy << 6;

        __bf16* ldsA = smem;
        __bf16* ldsB = smem + 2048;
        const __bf16* gA = comb + (size_t)(rb + (t & 63)) * 512 + (t >> 6) * 8;
        const __bf16* gB = woutB + (size_t)(n0 + (t & 63)) * 512 + (t >> 6) * 8;
        __bf16* lA = ldsA + t * 8;
        __bf16* lB = ldsB + t * 8;

        f32x4 acc[4];
#pragma unroll
        for (int ct = 0; ct < 4; ct++) acc[ct] = (f32x4){0.f, 0.f, 0.f, 0.f};

        for (int kt = 0; kt < 512; kt += 32) {
            gload16(gA + kt, lA);
            gload16(gB + kt, lB);
            __syncthreads();

            int tr = w * 16 + lr;
            bf16x8 af = *reinterpret_cast<const bf16x8*>(ldsA + seg * 512 + tr * 8);
#pragma unroll
            for (int ct = 0; ct < 4; ct++) {
                bf16x8 bb = *reinterpret_cast<const bf16x8*>(ldsB + seg * 512 + (ct * 16 + lr) * 8);
                acc[ct] = __builtin_amdgcn_mfma_f32_16x16x32_bf16(af, bb, acc[ct], 0, 0, 0);
            }
            __syncthreads();
        }

#pragma unroll
        for (int ct = 0; ct < 4; ct++) {
            int col = n0 + ct * 16 + lr;
            float bo = b_out[col];
#pragma unroll
            for (int r = 0; r < 4; r++) {
                int row = rb + w * 16 + seg * 4 + r;
                size_t idx = (size_t)row * 256 + col;
                float acs = tanhf(acc[ct][r] + bo);
                float ng = (float)comb[(size_t)row * 512 + 256 + col];
                bf16x2 us = *reinterpret_cast<const bf16x2*>(ugsg + idx * 2);
                float ug = (float)us.x, sg = (float)us.y;
                float curr = ng + sg * acs;
                out[idx] = curr + ug * (hid[idx] - curr);
            }
        }
    }
}

extern "C" void kernel_launch(void* const* d_in, const int* in_sizes, int n_in,
                              void* d_out, int out_size, void* d_ws, size_t ws_size,
                              hipStream_t stream) {
    const float* input_t = (const float*)d_in[0];
    const float* hidden  = (const float*)d_in[1];
    const float* w_ih    = (const float*)d_in[2];
    const float* b_ih    = (const float*)d_in[3];
    const float* w_hh    = (const float*)d_in[4];
    const float* b_hh    = (const float*)d_in[5];
    const float* w_out   = (const float*)d_in[6];
    const float* b_out   = (const float*)d_in[7];
    const float* memory  = (const float*)d_in[8];
    float* out = (float*)d_out;
    __bf16* base = (__bf16*)d_ws;

    int occ = 0;
    hipError_t oe = hipOccupancyMaxActiveBlocksPerMultiprocessor(&occ, fused_kernel, 256, 0);
    if (oe != hipSuccess || occ < 1) occ = 1;
    int nb = occ * 256;          // 256 CUs on MI355X
    if (nb > 1024) nb = 1024;    // >= #tiles; phases are grid-strided anyway

    void* args[] = {
        (void*)&input_t, (void*)&hidden, (void*)&w_ih, (void*)&b_ih,
        (void*)&w_hh, (void*)&b_hh, (void*)&w_out, (void*)&b_out,
        (void*)&memory, (void*)&out, (void*)&base
    };
    hipLaunchCooperativeKernel((const void*)fused_kernel, dim3(nb), dim3(256),
                               args, 0, stream);
}

// Round 6
// 218.166 us; speedup vs baseline: 2.4431x; 2.4431x over previous
//
#include <hip/hip_runtime.h>
#include <stdint.h>

#define B_N 16384
#define H_N 256
#define IN_W 258
#define GX_N 70
#define GY_N 70
#define SW_N 2
#define KK_N 25

typedef __bf16 bf16x8 __attribute__((ext_vector_type(8)));
typedef __bf16 bf16x4 __attribute__((ext_vector_type(4)));
typedef __bf16 bf16x2 __attribute__((ext_vector_type(2)));
typedef float f32x4 __attribute__((ext_vector_type(4)));

#define AS1 __attribute__((address_space(1)))
#define AS3 __attribute__((address_space(3)))

static __device__ __forceinline__ void gload16(const void* g, void* l) {
    __builtin_amdgcn_global_load_lds((const AS1 uint32_t*)g, (AS3 uint32_t*)l, 16, 0, 0);
}

// ---- ws layout (bf16 elements) ----
// AB    at 0        : [16384][512]  ([feat|hid])
// wfull at 8388608  : [1024][512]   rows j=c*256+col, c in {r,i,s,n};
//                     k<256 -> wih[base_c+col][k], k>=256 -> whh[base_c+col][k-256]
//                     base_c = {0,256,768,512}
// woutB at 8912896  : [256][512]
// comb  at 9043968  : [16384][512]  ([mix|q])
// ugsg  at 17432576 : [16384][256][2] (ug,sg interleaved)
#define E_AB   8388608ULL
#define E_WF   8912896ULL
#define E_WOUT 9043968ULL
#define E_COMB 9043968ULL
#define E_UGSG 17432576ULL

__global__ __launch_bounds__(256) void cast_kernel(
    const float* __restrict__ in_t, const float* __restrict__ hid,
    const float* __restrict__ wih, const float* __restrict__ whh,
    const float* __restrict__ wout, __bf16* __restrict__ dst)
{
    size_t g = (size_t)blockIdx.x * blockDim.x + threadIdx.x;
    size_t stride = (size_t)gridDim.x * blockDim.x;
    for (size_t e = g * 4; e < E_WOUT; e += stride * 4) {
        const float* src;
        if (e < E_AB) {
            size_t row = e >> 9;
            size_t c = e & 511;
            src = (c < 256) ? (in_t + row * IN_W + c) : (hid + row * 256 + (c - 256));
        } else if (e < E_WF) {
            size_t off = e - E_AB;
            size_t j = off >> 9;
            size_t k = off & 511;
            size_t c = j >> 8;
            size_t col = j & 255;
            size_t cb = (c == 0) ? 0 : (c == 1) ? 256 : (c == 2) ? 768 : 512;
            const float* srcm = (k < 256) ? wih : whh;
            src = srcm + (cb + col) * 256 + (k & 255);
        } else {
            src = wout + (e - E_WF);
        }
        bf16x4 o;
        o.x = (__bf16)src[0];
        o.y = (__bf16)src[1];
        o.z = (__bf16)src[2];
        o.w = (__bf16)src[3];
        *reinterpret_cast<bf16x4*>(dst + e) = o;
    }
}

// Fused gates GEMM, K=512 concat form, LDS-staged, BK=64 (8 barrier-steps).
// block = 128 rows x 32 hcols, 4 waves (each 32 rows x 32 cols).
// LDS seg-major: slot = kseg*128 + row, 8 bf16 per slot (16B) -> conflict-free
// ds_read_b128 and global_load_lds-compatible (wave-uniform base + lane*16).
// grid = (128 row-tiles, 8 h-tiles): id%8 = rx%8 -> same-row tiles share XCD.
__global__ __launch_bounds__(256, 4) void gates_gemm(
    const __bf16* __restrict__ AB, const __bf16* __restrict__ wfull,
    const float* __restrict__ b_ih, const float* __restrict__ b_hh,
    __bf16* __restrict__ comb, __bf16* __restrict__ ugsg)
{
    __shared__ __bf16 ldsA[8192], ldsB[8192];  // 128 x 64k each, 16 KB each
    const int t = threadIdx.x;
    const int lane = t & 63, w = t >> 6;
    const int lr = lane & 15, seg = lane >> 4;
    const int rb = blockIdx.x * 128;
    const int h0 = blockIdx.y * 32;

    // staging: 1024 slots/buffer; thread t owns slots t + 256*m (m=0..3):
    // row = t&127 fixed, kseg = (t>>7) + 2*m.
    const int r_s = t & 127;
    const int s_lo = t >> 7;
    const __bf16* gA = AB + (size_t)(rb + r_s) * 512 + s_lo * 8;
    const int wr = ((r_s >> 5) << 8) + h0 + (r_s & 31);  // c*256 + h0 + col32
    const __bf16* gB = wfull + (size_t)wr * 512 + s_lo * 8;
    __bf16* lA = ldsA + t * 8;
    __bf16* lB = ldsB + t * 8;

    f32x4 acc_s[3][2][2], acc_ni[2][2], acc_nh[2][2];  // [..][hh][rh]
#pragma unroll
    for (int hh = 0; hh < 2; hh++)
#pragma unroll
        for (int rh = 0; rh < 2; rh++) {
#pragma unroll
            for (int c = 0; c < 3; c++) acc_s[c][hh][rh] = (f32x4){0.f, 0.f, 0.f, 0.f};
            acc_ni[hh][rh] = (f32x4){0.f, 0.f, 0.f, 0.f};
            acc_nh[hh][rh] = (f32x4){0.f, 0.f, 0.f, 0.f};
        }

#pragma unroll 1
    for (int half = 0; half < 2; half++) {
        for (int kt = half * 256; kt < half * 256 + 256; kt += 64) {
#pragma unroll
            for (int m = 0; m < 4; m++) {
                gload16(gA + kt + m * 16, lA + m * 2048);
                gload16(gB + kt + m * 16, lB + m * 2048);
            }
            __syncthreads();

#pragma unroll
            for (int ks = 0; ks < 2; ks++) {
                bf16x8 af[2];
#pragma unroll
                for (int rh = 0; rh < 2; rh++) {
                    int tr = w * 32 + rh * 16 + lr;
                    af[rh] = *reinterpret_cast<const bf16x8*>(ldsA + ((ks * 4 + seg) * 128 + tr) * 8);
                }
#pragma unroll
                for (int c = 0; c < 4; c++)
#pragma unroll
                    for (int hh = 0; hh < 2; hh++) {
                        int br = c * 32 + hh * 16 + lr;
                        bf16x8 bb = *reinterpret_cast<const bf16x8*>(ldsB + ((ks * 4 + seg) * 128 + br) * 8);
#pragma unroll
                        for (int rh = 0; rh < 2; rh++) {
                            if (c < 3)
                                acc_s[c][hh][rh] = __builtin_amdgcn_mfma_f32_16x16x32_bf16(af[rh], bb, acc_s[c][hh][rh], 0, 0, 0);
                            else if (half == 0)
                                acc_ni[hh][rh] = __builtin_amdgcn_mfma_f32_16x16x32_bf16(af[rh], bb, acc_ni[hh][rh], 0, 0, 0);
                            else
                                acc_nh[hh][rh] = __builtin_amdgcn_mfma_f32_16x16x32_bf16(af[rh], bb, acc_nh[hh][rh], 0, 0, 0);
                        }
                    }
            }
            __syncthreads();
        }
    }

#pragma unroll
    for (int hh = 0; hh < 2; hh++) {
        int col = h0 + hh * 16 + lr;
        float br_ = b_ih[col] + b_hh[col];
        float bi_ = b_ih[col + 256] + b_hh[col + 256];
        float bs_ = b_ih[col + 768] + b_hh[col + 768];
        float bni = b_ih[col + 512];
        float bnh = b_hh[col + 512];
#pragma unroll
        for (int rh = 0; rh < 2; rh++) {
#pragma unroll
            for (int r = 0; r < 4; r++) {
                int row = rb + w * 32 + rh * 16 + seg * 4 + r;
                float sr = acc_s[0][hh][rh][r] + br_;
                float si = acc_s[1][hh][rh][r] + bi_;
                float ss = acc_s[2][hh][rh][r] + bs_;
                float ni = acc_ni[hh][rh][r] + bni;
                float nh = acc_nh[hh][rh][r] + bnh;
                float rg = 1.f / (1.f + __expf(-sr));
                float ug = 1.f / (1.f + __expf(-si));
                float sg = 1.f / (1.f + __expf(-ss));
                float ng = tanhf(ni + rg * nh);
                comb[(size_t)row * 512 + 256 + col] = (__bf16)ng;
                bf16x2 us;
                us.x = (__bf16)ug;
                us.y = (__bf16)sg;
                *reinterpret_cast<bf16x2*>(ugsg + ((size_t)row * 256 + col) * 2) = us;
            }
        }
    }
}

// Attention: one wave per row, online softmax, f32x4 per lane.
__global__ __launch_bounds__(256) void attn_kernel(
    const float* __restrict__ in_t, const float* __restrict__ memory,
    __bf16* __restrict__ comb)
{
    const int w = threadIdx.x >> 6;
    const int lane = threadIdx.x & 63;
    const int b = blockIdx.x * 4 + w;
    const float* row_in = in_t + (size_t)b * IN_W;
    int gx = (int)row_in[256] + SW_N;
    int gy = (int)row_in[257] + SW_N;
    gx = min(max(gx, 0), GX_N - 1);
    gy = min(max(gy, 0), GY_N - 1);

    bf16x4 qb = *reinterpret_cast<const bf16x4*>(comb + (size_t)b * 512 + 256 + lane * 4);
    float q0 = (float)qb.x, q1 = (float)qb.y, q2 = (float)qb.z, q3 = (float)qb.w;

    float m = -INFINITY, d = 0.f;
    float o0 = 0.f, o1 = 0.f, o2 = 0.f, o3 = 0.f;
#pragma unroll
    for (int k = 0; k < KK_N; k++) {
        int i = k / 5, jj = k % 5;
        int xi = min(max(gx + i - SW_N, 0), GX_N - 1);
        int yj = min(max(gy + jj - SW_N, 0), GY_N - 1);
        const f32x4* cp = reinterpret_cast<const f32x4*>(memory + ((size_t)xi * GY_N + yj) * H_N);
        f32x4 v = cp[lane];
        float p = q0 * v.x + q1 * v.y + q2 * v.z + q3 * v.w;
        for (int off = 32; off; off >>= 1) p += __shfl_xor(p, off, 64);
        float a = (p == 0.f) ? -INFINITY : p;
        float mn = fmaxf(m, a);
        if (mn != -INFINITY) {
            float alpha = __expf(m - mn);
            float e = __expf(a - mn);
            d = d * alpha + e;
            o0 = o0 * alpha + e * v.x;
            o1 = o1 * alpha + e * v.y;
            o2 = o2 * alpha + e * v.z;
            o3 = o3 * alpha + e * v.w;
            m = mn;
        }
    }
    float inv = (d != 0.f) ? 1.f / d : 0.f;
    bf16x4 ob;
    ob.x = (__bf16)(o0 * inv);
    ob.y = (__bf16)(o1 * inv);
    ob.z = (__bf16)(o2 * inv);
    ob.w = (__bf16)(o3 * inv);
    *reinterpret_cast<bf16x4*>(comb + (size_t)b * 512 + lane * 4) = ob;
}

// Output GEMM (K=512) + tanh + blend, LDS-staged, BK=64.
// block = 128 rows x 64 cols; grid (128 row-tiles, 4 col-tiles), XCD-affine.
__global__ __launch_bounds__(256, 4) void out_gemm(
    const __bf16* __restrict__ comb, const __bf16* __restrict__ woB,
    const float* __restrict__ b_out, const __bf16* __restrict__ ugsg,
    const float* __restrict__ hidden, float* __restrict__ out)
{
    __shared__ __bf16 ldsA[8192], ldsB[4096];  // A 128x64k, B 64x64k
    const int t = threadIdx.x;
    const int lane = t & 63, w = t >> 6;
    const int lr = lane & 15, seg = lane >> 4;
    const int rb = blockIdx.x * 128;
    const int n0 = blockIdx.y * 64;

    // A staging: 1024 slots (kseg*128+row); thread t: row=t&127, kseg=(t>>7)+2m
    const int r_s = t & 127;
    const int s_lo = t >> 7;
    const __bf16* gA = comb + (size_t)(rb + r_s) * 512 + s_lo * 8;
    __bf16* lA = ldsA + t * 8;
    // B staging: 512 slots (kseg*64+nrow); thread t: nrow=t&63, kseg=(t>>6)+4m
    const __bf16* gB = woB + (size_t)(n0 + (t & 63)) * 512 + (t >> 6) * 8;
    __bf16* lB = ldsB + t * 8;

    f32x4 acc[2][4];  // [rowhalf][coltile]
#pragma unroll
    for (int rh = 0; rh < 2; rh++)
#pragma unroll
        for (int ct = 0; ct < 4; ct++) acc[rh][ct] = (f32x4){0.f, 0.f, 0.f, 0.f};

    for (int kt = 0; kt < 512; kt += 64) {
#pragma unroll
        for (int m = 0; m < 4; m++) gload16(gA + kt + m * 16, lA + m * 2048);
#pragma unroll
        for (int m = 0; m < 2; m++) gload16(gB + kt + m * 32, lB + m * 2048);
        __syncthreads();

#pragma unroll
        for (int ks = 0; ks < 2; ks++) {
            bf16x8 af[2];
#pragma unroll
            for (int rh = 0; rh < 2; rh++) {
                int tr = w * 32 + rh * 16 + lr;
                af[rh] = *reinterpret_cast<const bf16x8*>(ldsA + ((ks * 4 + seg) * 128 + tr) * 8);
            }
#pragma unroll
            for (int ct = 0; ct < 4; ct++) {
                bf16x8 bb = *reinterpret_cast<const bf16x8*>(ldsB + ((ks * 4 + seg) * 64 + ct * 16 + lr) * 8);
#pragma unroll
                for (int rh = 0; rh < 2; rh++)
                    acc[rh][ct] = __builtin_amdgcn_mfma_f32_16x16x32_bf16(af[rh], bb, acc[rh][ct], 0, 0, 0);
            }
        }
        __syncthreads();
    }

#pragma unroll
    for (int ct = 0; ct < 4; ct++) {
        int col = n0 + ct * 16 + lr;
        float bo = b_out[col];
#pragma unroll
        for (int rh = 0; rh < 2; rh++) {
#pragma unroll
            for (int r = 0; r < 4; r++) {
                int row = rb + w * 32 + rh * 16 + seg * 4 + r;
                size_t idx = (size_t)row * 256 + col;
                float acs = tanhf(acc[rh][ct][r] + bo);
                float ng = (float)comb[(size_t)row * 512 + 256 + col];
                bf16x2 us = *reinterpret_cast<const bf16x2*>(ugsg + idx * 2);
                float ug = (float)us.x, sg = (float)us.y;
                float curr = ng + sg * acs;
                out[idx] = curr + ug * (hidden[idx] - curr);
            }
        }
    }
}

extern "C" void kernel_launch(void* const* d_in, const int* in_sizes, int n_in,
                              void* d_out, int out_size, void* d_ws, size_t ws_size,
                              hipStream_t stream) {
    const float* input_t = (const float*)d_in[0];
    const float* hidden  = (const float*)d_in[1];
    const float* w_ih    = (const float*)d_in[2];
    const float* b_ih    = (const float*)d_in[3];
    const float* w_hh    = (const float*)d_in[4];
    const float* b_hh    = (const float*)d_in[5];
    const float* w_out   = (const float*)d_in[6];
    const float* b_out   = (const float*)d_in[7];
    const float* memory  = (const float*)d_in[8];
    float* out = (float*)d_out;

    __bf16* base  = (__bf16*)d_ws;
    __bf16* AB    = base;
    __bf16* wfull = base + E_AB;
    __bf16* woutB = base + E_WF;
    __bf16* comb  = base + E_COMB;
    __bf16* ugsg  = base + E_UGSG;

    cast_kernel<<<4096, 256, 0, stream>>>(input_t, hidden, w_ih, w_hh, w_out, base);
    gates_gemm<<<dim3(128, 8), 256, 0, stream>>>(AB, wfull, b_ih, b_hh, comb, ugsg);
    attn_kernel<<<4096, 256, 0, stream>>>(input_t, memory, comb);
    out_gemm<<<dim3(128, 4), 256, 0, stream>>>(comb, woutB, b_out, ugsg, hidden, out);
}